// Round 7
// baseline (105.470 us; speedup 1.0000x reference)
//
#include <hip/hip_runtime.h>
#include <stdint.h>

#define PDIM 512
#define T_   66
#define EMB  128
#define NS   24
#define NM   40
#define NBS  42   // 66-24 base screen rows (ids unique per sample)
#define NBM  26   // 66-40 base mini rows
#define NI   70
#define CONT 32
#define OUTW 21408   // 32 + 66*128 + 66*128 + 70*64

typedef __attribute__((ext_vector_type(4))) float f32x4;
typedef __attribute__((ext_vector_type(8))) unsigned short u16x8;
typedef __attribute__((ext_vector_type(8))) __bf16 bf16x8;

static __device__ __forceinline__ unsigned short f2bf(float x) {
  union { float f; unsigned u; } v; v.f = x;
  unsigned r = (v.u + 0x7FFFu + ((v.u >> 16) & 1u)) >> 16;
  return (unsigned short)r;
}

static __device__ __forceinline__ f32x4 mfma16(u16x8 a, u16x8 b, f32x4 c) {
  return __builtin_amdgcn_mfma_f32_16x16x32_bf16(
      __builtin_bit_cast(bf16x8, a), __builtin_bit_cast(bf16x8, b), c, 0, 0, 0);
}

// ---------------------------------------------------------------------------
// Kernel 0: batch-independent precompute (unchanged).
// ---------------------------------------------------------------------------
__global__ __launch_bounds__(PDIM) void precomp(
    const float* __restrict__ char_emb,
    const float* __restrict__ Ws1, const float* __restrict__ bs1,
    const float* __restrict__ Ws2, const float* __restrict__ bs2,
    const float* __restrict__ Wm1, const float* __restrict__ bm1,
    const float* __restrict__ Wm2, const float* __restrict__ bm2,
    float* __restrict__ base_h_s, float* __restrict__ base_h_m,
    float* __restrict__ base_out_s, float* __restrict__ base_out_m,
    unsigned short* __restrict__ w2s_swz, unsigned short* __restrict__ w2m_swz) {
  const int bb = blockIdx.x, tid = threadIdx.x;
  if (bb < T_) {
    const int t = bb;
    const int quarter = tid >> 7;      // 0..3
    const int col = tid & 127;
    const int mlp = quarter & 1;       // 0 screen, 1 mini
    const int kh = quarter >> 1;       // k half
    const float* W1 = mlp ? Wm1 : Ws1;
    const float* W2 = mlp ? Wm2 : Ws2;
    const float* b1 = mlp ? bm1 : bs1;
    const float* b2 = mlp ? bm2 : bs2;
    float* bh = mlp ? base_h_m : base_h_s;
    float* bo = mlp ? base_out_m : base_out_s;
    __shared__ float part[4][EMB];
    __shared__ float h[2][EMB];
    float acc = 0.f;
#pragma unroll 8
    for (int f = kh * 64; f < kh * 64 + 64; ++f)
      acc += char_emb[t * EMB + f] * W1[f * EMB + col];
    part[quarter][col] = acc;
    __syncthreads();
    if (tid < 256) {
      const float v = b1[col] + part[mlp][col] + part[2 + mlp][col];
      bh[t * EMB + col] = v;           // pre-relu (needed for feat correction)
      h[mlp][col] = fmaxf(v, 0.f);
    }
    __syncthreads();
    float acc2 = 0.f;
#pragma unroll 8
    for (int i = kh * 64; i < kh * 64 + 64; ++i)
      acc2 += h[mlp][i] * W2[i * EMB + col];
    part[quarter][col] = acc2;
    __syncthreads();
    if (tid < 256)
      bo[t * EMB + col] = b2[col] + part[mlp][col] + part[2 + mlp][col];
  } else {
    const int mlp = bb - T_;
    const float* W2 = mlp ? Wm2 : Ws2;
    unsigned short* dst = mlp ? w2m_swz : w2s_swz;
    for (int idx = tid; idx < 8 * 4 * 64 * 8; idx += PDIM) {
      const int e = idx & 7, lane = (idx >> 3) & 63, kk = (idx >> 9) & 3, n = idx >> 11;
      const int k = kk * 32 + (lane >> 4) * 8 + e;
      const int col = n * 16 + (lane & 15);
      dst[idx] = f2bf(W2[k * EMB + col]);
    }
  }
}

// ---------------------------------------------------------------------------
// Kernel A: detection rows only. One block per sample, 512 threads (8 waves,
// wave w owns col-tile w). LDS-staged det rows -> full-line NT writes.
// Writes 64 rows x 512 B per sample = 134 MB total.
// ---------------------------------------------------------------------------
__global__ __launch_bounds__(512) void compute_det(
    const float* __restrict__ sfeat,
    const float* __restrict__ mfeat,
    const float* __restrict__ Ws1,
    const float* __restrict__ bs2,
    const float* __restrict__ Wm1,
    const float* __restrict__ bm2,
    const int* __restrict__ sids,
    const int* __restrict__ mids,
    const float* __restrict__ base_h_s, const float* __restrict__ base_h_m,
    const unsigned short* __restrict__ w2s_swz, const unsigned short* __restrict__ w2m_swz,
    float* __restrict__ out) {
  const int b = blockIdx.x, tid = threadIdx.x;

  __shared__ int s_id[NS], m_id[NM];
  __shared__ float s_f[NS * 4], m_f[NM * 2];
  __shared__ u16x8 h_frag[5 * 4 * 64];      // 20 KB
  __shared__ float det_out[48 * 132];       // 25.3 KB, stride 132 (bank pad)

  // ---- meta ----
  if (tid < NS) s_id[tid] = sids[b * NS + tid];
  if (tid < NM) m_id[tid] = mids[b * NM + tid];
  if (tid < NS * 4) s_f[tid] = sfeat[b * NS * 4 + tid];
  if (tid < NM * 2) m_f[tid] = mfeat[b * NM * 2 + tid];
  __syncthreads();

  // ---- build h fragments ----
  for (int u = tid; u < 5 * 4 * 64; u += 512) {
    const int ln = u & 63, kk = (u >> 6) & 3, tile = u >> 8;
    const int gg = ln >> 4, rr = ln & 15;
    const int k0 = kk * 32 + gg * 8;
    const bool scr = tile < 2;
    const int j = scr ? tile * 16 + rr : (tile - 2) * 16 + rr;
    const int nd = scr ? NS : NM;
    float v[8];
    if (j < nd) {
      const int t = scr ? s_id[j] : m_id[j];
      const float* bh = (scr ? base_h_s : base_h_m) + t * EMB + k0;
#pragma unroll
      for (int e = 0; e < 8; ++e) v[e] = bh[e];
      if (scr) {
        const float* fp = &s_f[j * 4];
#pragma unroll
        for (int c = 0; c < 4; ++c) {
          const float fc = fp[c];
          const float* wp = Ws1 + (128 + c) * EMB + k0;
#pragma unroll
          for (int e = 0; e < 8; ++e) v[e] += fc * wp[e];
        }
      } else {
        const float* fp = &m_f[j * 2];
#pragma unroll
        for (int c = 0; c < 2; ++c) {
          const float fc = fp[c];
          const float* wp = Wm1 + (128 + c) * EMB + k0;
#pragma unroll
          for (int e = 0; e < 8; ++e) v[e] += fc * wp[e];
        }
      }
#pragma unroll
      for (int e = 0; e < 8; ++e) v[e] = fmaxf(v[e], 0.f);
    } else {
#pragma unroll
      for (int e = 0; e < 8; ++e) v[e] = 0.f;  // pad rows: NaN-free MFMA
    }
    u16x8 pk;
#pragma unroll
    for (int e = 0; e < 8; ++e) pk[e] = f2bf(v[e]);
    h_frag[u] = pk;
  }
  __syncthreads();

  const int lane = tid & 63, w = tid >> 6;
  const int g = lane >> 4, r = lane & 15;
  const int col = w * 16 + r;
  float* outS = out + (size_t)b * OUTW + CONT;
  float* outM = outS + T_ * EMB;

  // ---- screen GEMM -> LDS ----
  {
    u16x8 bf[4];
    const float bias = bs2[col];
#pragma unroll
    for (int kk = 0; kk < 4; ++kk)
      bf[kk] = reinterpret_cast<const u16x8*>(w2s_swz)[(w * 4 + kk) * 64 + lane];
#pragma unroll
    for (int m = 0; m < 2; ++m) {
      f32x4 acc = {bias, bias, bias, bias};
#pragma unroll
      for (int kk = 0; kk < 4; ++kk)
        acc = mfma16(h_frag[(m * 4 + kk) * 64 + lane], bf[kk], acc);
#pragma unroll
      for (int q = 0; q < 4; ++q)
        det_out[(m * 16 + g * 4 + q) * 132 + col] = acc[q];
    }
  }
  __syncthreads();
  // ---- write screen det rows (full lines, NT) ----
  for (int u = tid; u < NS * 32; u += 512) {
    const int d = u >> 5, q = u & 31;
    const f32x4 v = *reinterpret_cast<const f32x4*>(&det_out[d * 132 + q * 4]);
    __builtin_nontemporal_store(v, reinterpret_cast<f32x4*>(outS + s_id[d] * EMB) + q);
  }
  __syncthreads();   // det_out reused below

  // ---- minimap GEMM -> LDS ----
  {
    u16x8 bf[4];
    const float bias = bm2[col];
#pragma unroll
    for (int kk = 0; kk < 4; ++kk)
      bf[kk] = reinterpret_cast<const u16x8*>(w2m_swz)[(w * 4 + kk) * 64 + lane];
#pragma unroll
    for (int m = 0; m < 3; ++m) {
      f32x4 acc = {bias, bias, bias, bias};
#pragma unroll
      for (int kk = 0; kk < 4; ++kk)
        acc = mfma16(h_frag[((m + 2) * 4 + kk) * 64 + lane], bf[kk], acc);
#pragma unroll
      for (int q = 0; q < 4; ++q)
        det_out[(m * 16 + g * 4 + q) * 132 + col] = acc[q];
    }
  }
  __syncthreads();
  // ---- write minimap det rows ----
  for (int u = tid; u < NM * 32; u += 512) {
    const int d = u >> 5, q = u & 31;
    const f32x4 v = *reinterpret_cast<const f32x4*>(&det_out[d * 132 + q * 4]);
    __builtin_nontemporal_store(v, reinterpret_cast<f32x4*>(outM + m_id[d] * EMB) + q);
  }
}

// ---------------------------------------------------------------------------
// Kernel B: memset-shaped writer. One block per sample, 256 threads, tiny
// LDS/VGPR -> 8 blocks/CU (32 waves/CU). Base rows + items + continuous:
// 217 MB of pure f32x4 NT streaming.
// ---------------------------------------------------------------------------
__global__ __launch_bounds__(256) void writer(
    const float* __restrict__ contf,
    const float* __restrict__ item_emb,
    const int* __restrict__ sids,
    const int* __restrict__ mids,
    const int* __restrict__ items,
    const float* __restrict__ base_out_s, const float* __restrict__ base_out_m,
    float* __restrict__ out) {
  const int b = blockIdx.x, tid = threadIdx.x;
  __shared__ int listS[NBS], listM[NBM];
  __shared__ short s_item[NI];
  __shared__ int mapS[T_], mapM[T_];
  __shared__ int cS, cM;

  if (tid == 0) { cS = 0; cM = 0; }
  if (tid < T_) { mapS[tid] = 0; mapM[tid] = 0; }
  __syncthreads();
  if (tid < NS) mapS[sids[b * NS + tid]] = 1;
  if (tid < NM) mapM[mids[b * NM + tid]] = 1;
  if (tid < NI) s_item[tid] = (short)items[b * NI + tid];
  __syncthreads();
  if (tid < T_ && !mapS[tid]) listS[atomicAdd(&cS, 1)] = tid;
  if (tid < T_ && !mapM[tid]) listM[atomicAdd(&cM, 1)] = tid;
  __syncthreads();

  float* outB = out + (size_t)b * OUTW;
  float* outS = outB + CONT;
  float* outM = outS + T_ * EMB;
  float* outI = outM + T_ * EMB;

  // slot space: 42*32 | 26*32 | 70*16 | 8  = 1344 | 832 | 1120 | 8 = 3304
#pragma unroll 2
  for (int u = tid; u < 3304; u += 256) {
    f32x4 v; float* dst;
    if (u < 1344) {
      const int i = u >> 5, q = u & 31;
      const int t = listS[i];
      v = reinterpret_cast<const f32x4*>(base_out_s + t * EMB)[q];
      dst = outS + t * EMB + q * 4;
    } else if (u < 2176) {
      const int v2 = u - 1344, i = v2 >> 5, q = v2 & 31;
      const int t = listM[i];
      v = reinterpret_cast<const f32x4*>(base_out_m + t * EMB)[q];
      dst = outM + t * EMB + q * 4;
    } else if (u < 3296) {
      const int v2 = u - 2176, j = v2 >> 4, q = v2 & 15;
      v = reinterpret_cast<const f32x4*>(item_emb + (int)s_item[j] * 64)[q];
      dst = outI + j * 64 + q * 4;
    } else {
      const int q = u - 3296;
      v = reinterpret_cast<const f32x4*>(contf + (size_t)b * CONT)[q];
      dst = outB + q * 4;
    }
    __builtin_nontemporal_store(v, reinterpret_cast<f32x4*>(dst));
  }
}

// ---------------------------------------------------------------------------
extern "C" void kernel_launch(void* const* d_in, const int* in_sizes, int n_in,
                              void* d_out, int out_size, void* d_ws, size_t ws_size,
                              hipStream_t stream) {
  const float* contf    = (const float*)d_in[0];
  const float* sfeat    = (const float*)d_in[1];
  const float* mfeat    = (const float*)d_in[2];
  const float* char_emb = (const float*)d_in[3];
  const float* item_emb = (const float*)d_in[4];
  const float* Ws1 = (const float*)d_in[5];
  const float* bs1 = (const float*)d_in[6];
  const float* Ws2 = (const float*)d_in[7];
  const float* bs2 = (const float*)d_in[8];
  const float* Wm1 = (const float*)d_in[9];
  const float* bm1 = (const float*)d_in[10];
  const float* Wm2 = (const float*)d_in[11];
  const float* bm2 = (const float*)d_in[12];
  const int* sids  = (const int*)d_in[13];
  const int* mids  = (const int*)d_in[14];
  const int* items = (const int*)d_in[15];
  float* out = (float*)d_out;

  const int B = in_sizes[0] / CONT;

  // workspace layout (bytes): 4x base tables (33792 each) + 2x bf16 W2 (32768 each)
  char* ws = (char*)d_ws;
  float* base_h_s   = (float*)(ws + 0);
  float* base_h_m   = (float*)(ws + 33792);
  float* base_out_s = (float*)(ws + 67584);
  float* base_out_m = (float*)(ws + 101376);
  unsigned short* w2s = (unsigned short*)(ws + 135168);
  unsigned short* w2m = (unsigned short*)(ws + 167936);

  precomp<<<T_ + 2, PDIM, 0, stream>>>(char_emb, Ws1, bs1, Ws2, bs2, Wm1, bm1, Wm2, bm2,
                                       base_h_s, base_h_m, base_out_s, base_out_m, w2s, w2m);
  compute_det<<<B, 512, 0, stream>>>(sfeat, mfeat, Ws1, bs2, Wm1, bm2, sids, mids,
                                     base_h_s, base_h_m, w2s, w2m, out);
  writer<<<B, 256, 0, stream>>>(contf, item_emb, sids, mids, items,
                                base_out_s, base_out_m, out);
}